// Round 6
// baseline (468.245 us; speedup 1.0000x reference)
//
#include <hip/hip_runtime.h>
#include <math.h>

// Problem constants (fixed by setup_inputs)
#define Nn 4
#define Ll 4096
#define Ss 256
#define Cc 256
#define FC 8
#define SC 32

#define LSTR 132                        // k-major LDS stride (words)
#define PHI(k) ((((k) >> 3) & 3) << 2)  // row-XOR swizzle (const per k-octet)

// ---------------------------------------------------------------------------
// k-major fp32 GEMM tile, acc[8][8] += A[row0..+128][:] @ W[cb0..+128][:]^T+b.
// 256 threads; thread rows {4tr+i, 64+4tr+i}, cols {4tc+c, 64+4tc+c}.
// LDS word (r,k) at k*LSTR + (r ^ PHI(k)).
// Staging: each thread owns a 4-row x 4-k block -> 4x4 register transpose ->
// 4 ds_write_b128 (PHI constant within the quad). Global loads coalesced.
// Inner loop: explicit k+1 register double-buffer of the 4 ds_read_b128 so
// LDS latency hides behind the 64 fmas even at 1 wave/SIMD.
// ---------------------------------------------------------------------------
__device__ __forceinline__ void gemm_tile(
    const float* __restrict__ A, const float* __restrict__ W,
    const float* __restrict__ bias, size_t row0, int cb0,
    float* __restrict__ As, float* __restrict__ Bs, int t, float acc[8][8]) {
  int tc = t & 15, tr = (t >> 4) & 15;
  int jq = t & 7, r0s = 4 * (t >> 3);            // staging 4x4 block
  int phS = ((jq >> 1) & 3) << 2;                // PHI(4jq+q), q<4
  int woff = (4 * jq) * LSTR + (r0s ^ phS);

  float4 bb0 = *(const float4*)&bias[cb0 + 4 * tc];
  float4 bb1 = *(const float4*)&bias[cb0 + 64 + 4 * tc];
#pragma unroll
  for (int i = 0; i < 8; i++) {
    acc[i][0] = bb0.x; acc[i][1] = bb0.y; acc[i][2] = bb0.z; acc[i][3] = bb0.w;
    acc[i][4] = bb1.x; acc[i][5] = bb1.y; acc[i][6] = bb1.z; acc[i][7] = bb1.w;
  }

  float4 pa[4], pb[4];
#pragma unroll
  for (int i = 0; i < 4; i++) {
    pa[i] = *(const float4*)(A + (row0 + r0s + i) * Cc + 4 * jq);
    pb[i] = *(const float4*)(W + (size_t)(cb0 + r0s + i) * Cc + 4 * jq);
  }

  for (int kt = 0; kt < 8; kt++) {
    __syncthreads();
    // commit staged 4x4 blocks with register transpose -> b128 writes
#pragma unroll
    for (int q = 0; q < 4; q++) {
      float4 wa, wb;
      wa.x = ((const float*)&pa[0])[q]; wa.y = ((const float*)&pa[1])[q];
      wa.z = ((const float*)&pa[2])[q]; wa.w = ((const float*)&pa[3])[q];
      wb.x = ((const float*)&pb[0])[q]; wb.y = ((const float*)&pb[1])[q];
      wb.z = ((const float*)&pb[2])[q]; wb.w = ((const float*)&pb[3])[q];
      *(float4*)&As[woff + q * LSTR] = wa;
      *(float4*)&Bs[woff + q * LSTR] = wb;
    }
    if (kt < 7) {
#pragma unroll
      for (int i = 0; i < 4; i++) {
        pa[i] = *(const float4*)(A + (row0 + r0s + i) * Cc + (kt + 1) * 32 + 4 * jq);
        pb[i] = *(const float4*)(W + (size_t)(cb0 + r0s + i) * Cc + (kt + 1) * 32 + 4 * jq);
      }
    }
    __syncthreads();

    int ia0 = 4 * tr, ib0 = 4 * tc;
    float4 a0, a1, b0, b1;
    a0 = *(const float4*)&As[ia0];            // k=0, PHI=0
    a1 = *(const float4*)&As[64 + ia0];
    b0 = *(const float4*)&Bs[ib0];
    b1 = *(const float4*)&Bs[64 + ib0];
#pragma unroll
    for (int k = 0; k < 32; k++) {
      float4 na0, na1, nb0, nb1;
      if (k < 31) {
        int kn = k + 1, ph = PHI(kn);
        int ja = ia0 ^ ph, jb = ib0 ^ ph;
        na0 = *(const float4*)&As[kn * LSTR + ja];
        na1 = *(const float4*)&As[kn * LSTR + 64 + ja];
        nb0 = *(const float4*)&Bs[kn * LSTR + jb];
        nb1 = *(const float4*)&Bs[kn * LSTR + 64 + jb];
      }
      const float* af0 = (const float*)&a0;
      const float* af1 = (const float*)&a1;
      const float* bf0 = (const float*)&b0;
      const float* bf1 = (const float*)&b1;
#pragma unroll
      for (int i = 0; i < 4; i++) {
#pragma unroll
        for (int c = 0; c < 4; c++) {
          acc[i][c]         = fmaf(af0[i], bf0[c], acc[i][c]);
          acc[i][c + 4]     = fmaf(af0[i], bf1[c], acc[i][c + 4]);
          acc[i + 4][c]     = fmaf(af1[i], bf0[c], acc[i + 4][c]);
          acc[i + 4][c + 4] = fmaf(af1[i], bf1[c], acc[i + 4][c + 4]);
        }
      }
      if (k < 31) { a0 = na0; a1 = na1; b0 = nb0; b1 = nb1; }
    }
  }
}

__device__ __forceinline__ void store_tile(
    float* __restrict__ C, size_t row0, int cb0, int ldc, int t,
    const float acc[8][8]) {
  int tc = t & 15, tr = (t >> 4) & 15;
#pragma unroll
  for (int i = 0; i < 8; i++) {
    int r = (i < 4) ? (4 * tr + i) : (64 + 4 * tr + (i - 4));
    float4 o0, o1;
    o0.x = acc[i][0]; o0.y = acc[i][1]; o0.z = acc[i][2]; o0.w = acc[i][3];
    o1.x = acc[i][4]; o1.y = acc[i][5]; o1.z = acc[i][6]; o1.w = acc[i][7];
    float* cr = C + (row0 + r) * (size_t)ldc + cb0;
    *(float4*)(cr + 4 * tc) = o0;
    *(float4*)(cr + 64 + 4 * tc) = o1;
  }
}

// ---------------------------------------------------------------------------
// Fused kernel 1. Blocks 0..255: x0p = x0 @ W0^T + b0 -> xn[16384][256].
// Blocks 256..287: c1 = center1 @ W1^T + b1 (M=1024,N=512) + split/norm
// epilogue -> cpn (l2-normalized point half), cval (raw value half).
// ---------------------------------------------------------------------------
__global__ __launch_bounds__(256) void x0p_c1_k(
    const float* __restrict__ x0, const float* __restrict__ W0,
    const float* __restrict__ b0, const float* __restrict__ center1,
    const float* __restrict__ W1, const float* __restrict__ b1,
    float* __restrict__ xn, float* __restrict__ cpn, float* __restrict__ cval) {
  __shared__ float As[32 * LSTR];  // 16.9 KB
  __shared__ float Bs[32 * LSTR];  // 16.9 KB
  int t = threadIdx.x;
  int tc = t & 15, tr = (t >> 4) & 15;
  int b = blockIdx.x;
  float acc[8][8];

  if (b < 256) {
    size_t row0 = (size_t)(b >> 1) * 128;
    int cb0 = (b & 1) * 128;
    gemm_tile(x0, W0, b0, row0, cb0, As, Bs, t, acc);
    store_tile(xn, row0, cb0, Cc, t, acc);
  } else {
    int b2 = b - 256;
    size_t row0 = (size_t)(b2 >> 2) * 128;  // M=1024 (n*256+s)
    int cb0 = (b2 & 3) * 128;               // N=512
    gemm_tile(center1, W1, b1, row0, cb0, As, Bs, t, acc);
    // epilogue: cols {cb0+4tc+c} (fiber fb) and {cb0+64+4tc+c} (fiber fb+1);
    // q = 4tc+c in 0..63; point iff q<32 <=> tc<8.
    int fb = cb0 >> 6;
#pragma unroll
    for (int i = 0; i < 8; i++) {
      int r = (i < 4) ? (4 * tr + i) : (64 + 4 * tr + (i - 4));
      int crow = (int)row0 + r;
      int nI = crow >> 8, s = crow & 255;
#pragma unroll
      for (int h = 0; h < 2; h++) {
        float s0 = acc[i][4 * h + 0], s1 = acc[i][4 * h + 1];
        float s2 = acc[i][4 * h + 2], s3 = acc[i][4 * h + 3];
        float ss = s0 * s0 + s1 * s1 + s2 * s2 + s3 * s3;
        ss += __shfl_xor(ss, 1, 64);
        ss += __shfl_xor(ss, 2, 64);
        ss += __shfl_xor(ss, 4, 64);  // sums the tc-octet (point lanes tc<8)
        float rin = 1.f / fmaxf(sqrtf(ss), 1e-12f);
        int f = fb + h;
        size_t base = (((size_t)nI * FC + f) * Ss + s) * SC;
        if (tc < 8) {
          float4 o; o.x = s0 * rin; o.y = s1 * rin; o.z = s2 * rin; o.w = s3 * rin;
          *(float4*)&cpn[base + 4 * tc] = o;
        } else {
          float4 o; o.x = s0; o.y = s1; o.z = s2; o.w = s3;
          *(float4*)&cval[base + 4 * (tc - 8)] = o;
        }
      }
    }
  }
}

// ---------------------------------------------------------------------------
// sim: per block one (n,f), 64 l-rows vs all 256 centers, K=32 (k-major LDS).
// Thread 8 rows {4tr+i, 32+4tr+i} x 8 centers {4tc+c, 128+4tc+c}: per k
// 4 ds_read_b128 + 64 fmaf, k+1 register double-buffered. X rows l2-norm'd
// during staging. Argmax of a*sim+b per row via 16-lane... 32-lane shfl_xor
// (min-index tie); gather c_value, scale by sigmoid(max), write dispatched
// IN PLACE over xn (block owns its l x channel region exclusively).
// ---------------------------------------------------------------------------
__global__ __launch_bounds__(256) void sim_k(
    float* __restrict__ xn, const float* __restrict__ cpn,
    const float* __restrict__ cval, const float* __restrict__ alphap,
    const float* __restrict__ betap) {
  __shared__ float Xs[32 * 68];    //  8.7 KB (stride 68, rows 0..63)
  __shared__ float Cs[32 * 260];   // 33.3 KB (stride 260, centers 0..255)
  int t = threadIdx.x;
  int tc = t & 31, tr = t >> 5;    // 32 thread-cols x 8 thread-rows
  int lt = blockIdx.x & 63;
  int nf = blockIdx.x >> 6;        // 0..31
  int f = nf & 7, nI = nf >> 3;
  int l0 = lt * 64;

  // stage centers: 512 4x4 (center x k) blocks, 2 per thread, reg-transpose
  const float* cp = cpn + (size_t)nf * Ss * SC;
#pragma unroll
  for (int it = 0; it < 2; it++) {
    int idx = t + 256 * it;
    int jq = idx & 7, c0 = 4 * (idx >> 3);
    int ph = ((jq >> 1) & 3) << 2;
    float4 v[4];
#pragma unroll
    for (int i = 0; i < 4; i++)
      v[i] = *(const float4*)(cp + (size_t)(c0 + i) * SC + 4 * jq);
#pragma unroll
    for (int q = 0; q < 4; q++) {
      float4 w;
      w.x = ((const float*)&v[0])[q]; w.y = ((const float*)&v[1])[q];
      w.z = ((const float*)&v[2])[q]; w.w = ((const float*)&v[3])[q];
      *(float4*)&Cs[(4 * jq + q) * 260 + (c0 ^ ph)] = w;
    }
  }
  // stage x rows 64x32 (threads 0..127), l2-normalized (8-lane shfl per row)
  if (t < 128) {
    int jq = t & 7, r0 = 4 * (t >> 3);
    int ph = ((jq >> 1) & 3) << 2;
    float4 v[4];
    float ssq[4];
#pragma unroll
    for (int i = 0; i < 4; i++) {
      v[i] = *(const float4*)(xn + ((size_t)nI * Ll + l0 + r0 + i) * Cc + f * SC + 4 * jq);
      ssq[i] = v[i].x * v[i].x + v[i].y * v[i].y + v[i].z * v[i].z + v[i].w * v[i].w;
    }
#pragma unroll
    for (int m = 1; m <= 4; m <<= 1)
#pragma unroll
      for (int i = 0; i < 4; i++) ssq[i] += __shfl_xor(ssq[i], m, 64);
#pragma unroll
    for (int i = 0; i < 4; i++) {
      float rin = 1.f / fmaxf(sqrtf(ssq[i]), 1e-12f);
      v[i].x *= rin; v[i].y *= rin; v[i].z *= rin; v[i].w *= rin;
    }
#pragma unroll
    for (int q = 0; q < 4; q++) {
      float4 w;
      w.x = ((const float*)&v[0])[q]; w.y = ((const float*)&v[1])[q];
      w.z = ((const float*)&v[2])[q]; w.w = ((const float*)&v[3])[q];
      *(float4*)&Xs[(4 * jq + q) * 68 + (r0 ^ ph)] = w;
    }
  }
  __syncthreads();

  float acc[8][8];
#pragma unroll
  for (int i = 0; i < 8; i++)
#pragma unroll
    for (int c = 0; c < 8; c++) acc[i][c] = 0.f;

  int ia0 = 4 * tr, ib0 = 4 * tc;
  float4 a0, a1, b0, b1;
  a0 = *(const float4*)&Xs[ia0];
  a1 = *(const float4*)&Xs[32 + ia0];
  b0 = *(const float4*)&Cs[ib0];
  b1 = *(const float4*)&Cs[128 + ib0];
#pragma unroll
  for (int k = 0; k < 32; k++) {
    float4 na0, na1, nb0, nb1;
    if (k < 31) {
      int kn = k + 1, ph = PHI(kn);
      int ja = ia0 ^ ph, jb = ib0 ^ ph;
      na0 = *(const float4*)&Xs[kn * 68 + ja];
      na1 = *(const float4*)&Xs[kn * 68 + 32 + ja];
      nb0 = *(const float4*)&Cs[kn * 260 + jb];
      nb1 = *(const float4*)&Cs[kn * 260 + 128 + jb];
    }
    const float* af0 = (const float*)&a0;
    const float* af1 = (const float*)&a1;
    const float* bf0 = (const float*)&b0;
    const float* bf1 = (const float*)&b1;
#pragma unroll
    for (int i = 0; i < 4; i++) {
#pragma unroll
      for (int c = 0; c < 4; c++) {
        acc[i][c]         = fmaf(af0[i], bf0[c], acc[i][c]);
        acc[i][c + 4]     = fmaf(af0[i], bf1[c], acc[i][c + 4]);
        acc[i + 4][c]     = fmaf(af1[i], bf0[c], acc[i + 4][c]);
        acc[i + 4][c + 4] = fmaf(af1[i], bf1[c], acc[i + 4][c + 4]);
      }
    }
    if (k < 31) { a0 = na0; a1 = na1; b0 = nb0; b1 = nb1; }
  }

  float a = alphap[0], bt = betap[0];
#pragma unroll
  for (int i = 0; i < 8; i++) {
    int row = (i < 4) ? (4 * tr + i) : (32 + 4 * tr + (i - 4));
    float best = -3.0e38f;
    int bi = 0;
#pragma unroll
    for (int c = 0; c < 8; c++) {
      float tv = fmaf(a, acc[i][c], bt);
      int s = (c < 4) ? (4 * tc + c) : (128 + 4 * tc + (c - 4));  // increasing
      if (tv > best) { best = tv; bi = s; }
    }
#pragma unroll
    for (int m = 1; m <= 16; m <<= 1) {  // reduce across the 32 tc-lanes
      float ov = __shfl_xor(best, m, 64);
      int oi = __shfl_xor(bi, m, 64);
      if (ov > best || (ov == best && oi < bi)) { best = ov; bi = oi; }
    }
    float mv = 1.f / (1.f + expf(-best));
    const float* cvp = cval + ((size_t)nf * Ss + bi) * SC;
    float* orow = xn + ((size_t)nI * Ll + l0 + row) * Cc + f * SC;
    orow[tc] = cvp[tc] * mv;
  }
}

// ---------------------------------------------------------------------------
// out = dispatched @ Wm^T + bm
// ---------------------------------------------------------------------------
__global__ __launch_bounds__(256) void out_k(
    const float* __restrict__ xn, const float* __restrict__ Wm,
    const float* __restrict__ bm, float* __restrict__ out) {
  __shared__ float As[32 * LSTR];
  __shared__ float Bs[32 * LSTR];
  int t = threadIdx.x;
  size_t row0 = (size_t)(blockIdx.x >> 1) * 128;
  int cb0 = (blockIdx.x & 1) * 128;
  float acc[8][8];
  gemm_tile(xn, Wm, bm, row0, cb0, As, Bs, t, acc);
  store_tile(out, row0, cb0, Cc, t, acc);
}

// ---------------------------------------------------------------------------
extern "C" void kernel_launch(void* const* d_in, const int* in_sizes, int n_in,
                              void* d_out, int out_size, void* d_ws, size_t ws_size,
                              hipStream_t stream) {
  const float* x0      = (const float*)d_in[0];
  const float* center1 = (const float*)d_in[1];
  const float* W0      = (const float*)d_in[2];
  const float* b0      = (const float*)d_in[3];
  const float* W1      = (const float*)d_in[4];
  const float* b1      = (const float*)d_in[5];
  const float* Wm      = (const float*)d_in[6];
  const float* bm      = (const float*)d_in[7];
  const float* alpha   = (const float*)d_in[8];
  const float* beta    = (const float*)d_in[9];
  float* out = (float*)d_out;
  float* ws  = (float*)d_ws;

  float* xn   = ws;                              // 16 MB: x0p, then dispatched in-place
  float* cpn  = xn + (size_t)Nn * Ll * Cc;       // 1 MB
  float* cval = cpn + (size_t)Nn * FC * Ss * SC; // 1 MB  (total 18 MB)

  x0p_c1_k<<<dim3(288), dim3(256), 0, stream>>>(
      x0, W0, b0, center1, W1, b1, xn, cpn, cval);
  sim_k<<<dim3(32 * 64), dim3(256), 0, stream>>>(xn, cpn, cval, alpha, beta);
  out_k<<<dim3(256), dim3(256), 0, stream>>>(xn, Wm, bm, out);
}

// Round 7
// 213.099 us; speedup vs baseline: 2.1973x; 2.1973x over previous
//
#include <hip/hip_runtime.h>
#include <math.h>

// Problem constants (fixed by setup_inputs)
#define Nn 4
#define Ll 4096
#define Ss 256
#define Cc 256
#define FC 8
#define SC 32

#define LSTR 132                        // k-major LDS stride (words)
#define PHI(k) ((((k) >> 3) & 3) << 2)  // row-XOR swizzle (const per k-octet)

// ---------------------------------------------------------------------------
// k-major fp32 GEMM tile, acc[8][8] = A[row0..+128][:] @ W[cb0..+128][:]^T + b.
// 256 threads; thread rows {4tr+i, 64+4tr+i}, cols {4tc+c, 64+4tc+c}.
// LDS word (r,k) at k*LSTR + (r ^ PHI(k)).
// Staging: thread owns a 4-row x 4-k block -> 4x4 register transpose -> 4
// ds_write_b128 (PHI const within the quad). Inner loop: read-then-use
// (VGPR-safe, round-5 proven). KEY: the kt+1 global prefetch is issued AFTER
// the post-staging __syncthreads, so its vmcnt drain lands at the NEXT
// barrier, hidden behind the whole 32-k compute phase (barrier-drain fix).
// ---------------------------------------------------------------------------
__device__ __forceinline__ void gemm_tile(
    const float* __restrict__ A, const float* __restrict__ W,
    const float* __restrict__ bias, size_t row0, int cb0,
    float* __restrict__ As, float* __restrict__ Bs, int t, float acc[8][8]) {
  int tc = t & 15, tr = (t >> 4) & 15;
  int jq = t & 7, r0s = 4 * (t >> 3);  // staging 4x4 block
  int phS = ((jq >> 1) & 3) << 2;      // PHI(4jq+q), q<4
  int woff = (4 * jq) * LSTR + (r0s ^ phS);

  float4 bb0 = *(const float4*)&bias[cb0 + 4 * tc];
  float4 bb1 = *(const float4*)&bias[cb0 + 64 + 4 * tc];
#pragma unroll
  for (int i = 0; i < 8; i++) {
    acc[i][0] = bb0.x; acc[i][1] = bb0.y; acc[i][2] = bb0.z; acc[i][3] = bb0.w;
    acc[i][4] = bb1.x; acc[i][5] = bb1.y; acc[i][6] = bb1.z; acc[i][7] = bb1.w;
  }

  float4 pa[4], pb[4];
#pragma unroll
  for (int i = 0; i < 4; i++) {
    pa[i] = *(const float4*)(A + (row0 + r0s + i) * Cc + 4 * jq);
    pb[i] = *(const float4*)(W + (size_t)(cb0 + r0s + i) * Cc + 4 * jq);
  }

  for (int kt = 0; kt < 8; kt++) {
    __syncthreads();  // reads of previous tile done before overwrite
    // commit staged 4x4 blocks with register transpose -> b128 writes
#pragma unroll
    for (int q = 0; q < 4; q++) {
      float4 wa, wb;
      wa.x = ((const float*)&pa[0])[q]; wa.y = ((const float*)&pa[1])[q];
      wa.z = ((const float*)&pa[2])[q]; wa.w = ((const float*)&pa[3])[q];
      wb.x = ((const float*)&pb[0])[q]; wb.y = ((const float*)&pb[1])[q];
      wb.z = ((const float*)&pb[2])[q]; wb.w = ((const float*)&pb[3])[q];
      *(float4*)&As[woff + q * LSTR] = wa;
      *(float4*)&Bs[woff + q * LSTR] = wb;
    }
    __syncthreads();  // staging visible
    // prefetch kt+1 NOW (after the barrier): latency hides behind compute,
    // and the next barrier's vmcnt(0) drain is then free.
    if (kt < 7) {
#pragma unroll
      for (int i = 0; i < 4; i++) {
        pa[i] = *(const float4*)(A + (row0 + r0s + i) * Cc + (kt + 1) * 32 + 4 * jq);
        pb[i] = *(const float4*)(W + (size_t)(cb0 + r0s + i) * Cc + (kt + 1) * 32 + 4 * jq);
      }
    }

    int ia0 = 4 * tr, ib0 = 4 * tc;
#pragma unroll 8
    for (int k = 0; k < 32; k++) {
      int ph = PHI(k);
      int ja = ia0 ^ ph, jb = ib0 ^ ph;
      float4 a0 = *(const float4*)&As[k * LSTR + ja];
      float4 a1 = *(const float4*)&As[k * LSTR + 64 + ja];
      float4 b0 = *(const float4*)&Bs[k * LSTR + jb];
      float4 b1 = *(const float4*)&Bs[k * LSTR + 64 + jb];
      const float* af0 = (const float*)&a0;
      const float* af1 = (const float*)&a1;
      const float* bf0 = (const float*)&b0;
      const float* bf1 = (const float*)&b1;
#pragma unroll
      for (int i = 0; i < 4; i++) {
#pragma unroll
        for (int c = 0; c < 4; c++) {
          acc[i][c]         = fmaf(af0[i], bf0[c], acc[i][c]);
          acc[i][c + 4]     = fmaf(af0[i], bf1[c], acc[i][c + 4]);
          acc[i + 4][c]     = fmaf(af1[i], bf0[c], acc[i + 4][c]);
          acc[i + 4][c + 4] = fmaf(af1[i], bf1[c], acc[i + 4][c + 4]);
        }
      }
    }
  }
}

__device__ __forceinline__ void store_tile(
    float* __restrict__ C, size_t row0, int cb0, int ldc, int t,
    const float acc[8][8]) {
  int tc = t & 15, tr = (t >> 4) & 15;
#pragma unroll
  for (int i = 0; i < 8; i++) {
    int r = (i < 4) ? (4 * tr + i) : (64 + 4 * tr + (i - 4));
    float4 o0, o1;
    o0.x = acc[i][0]; o0.y = acc[i][1]; o0.z = acc[i][2]; o0.w = acc[i][3];
    o1.x = acc[i][4]; o1.y = acc[i][5]; o1.z = acc[i][6]; o1.w = acc[i][7];
    float* cr = C + (row0 + r) * (size_t)ldc + cb0;
    *(float4*)(cr + 4 * tc) = o0;
    *(float4*)(cr + 64 + 4 * tc) = o1;
  }
}

// ---------------------------------------------------------------------------
// Fused kernel 1. Blocks 0..255: x0p = x0 @ W0^T + b0 -> xn[16384][256].
// Blocks 256..287: c1 = center1 @ W1^T + b1 (M=1024,N=512) + split/norm
// epilogue -> cpn (l2-normalized point half), cval (raw value half).
// ---------------------------------------------------------------------------
__global__ __launch_bounds__(256) void x0p_c1_k(
    const float* __restrict__ x0, const float* __restrict__ W0,
    const float* __restrict__ b0, const float* __restrict__ center1,
    const float* __restrict__ W1, const float* __restrict__ b1,
    float* __restrict__ xn, float* __restrict__ cpn, float* __restrict__ cval) {
  __shared__ float As[32 * LSTR];  // 16.9 KB
  __shared__ float Bs[32 * LSTR];  // 16.9 KB
  int t = threadIdx.x;
  int tc = t & 15, tr = (t >> 4) & 15;
  int b = blockIdx.x;
  float acc[8][8];

  if (b < 256) {
    size_t row0 = (size_t)(b >> 1) * 128;
    int cb0 = (b & 1) * 128;
    gemm_tile(x0, W0, b0, row0, cb0, As, Bs, t, acc);
    store_tile(xn, row0, cb0, Cc, t, acc);
  } else {
    int b2 = b - 256;
    size_t row0 = (size_t)(b2 >> 2) * 128;  // M=1024 (n*256+s)
    int cb0 = (b2 & 3) * 128;               // N=512
    gemm_tile(center1, W1, b1, row0, cb0, As, Bs, t, acc);
    // epilogue: cols {cb0+4tc+c} (fiber fb) and {cb0+64+4tc+c} (fiber fb+1);
    // q = 4tc+c in 0..63; point iff q<32 <=> tc<8.
    int fb = cb0 >> 6;
#pragma unroll
    for (int i = 0; i < 8; i++) {
      int r = (i < 4) ? (4 * tr + i) : (64 + 4 * tr + (i - 4));
      int crow = (int)row0 + r;
      int nI = crow >> 8, s = crow & 255;
#pragma unroll
      for (int h = 0; h < 2; h++) {
        float s0 = acc[i][4 * h + 0], s1 = acc[i][4 * h + 1];
        float s2 = acc[i][4 * h + 2], s3 = acc[i][4 * h + 3];
        float ss = s0 * s0 + s1 * s1 + s2 * s2 + s3 * s3;
        ss += __shfl_xor(ss, 1, 64);
        ss += __shfl_xor(ss, 2, 64);
        ss += __shfl_xor(ss, 4, 64);  // sums the tc-octet (point lanes tc<8)
        float rin = 1.f / fmaxf(sqrtf(ss), 1e-12f);
        int f = fb + h;
        size_t base = (((size_t)nI * FC + f) * Ss + s) * SC;
        if (tc < 8) {
          float4 o; o.x = s0 * rin; o.y = s1 * rin; o.z = s2 * rin; o.w = s3 * rin;
          *(float4*)&cpn[base + 4 * tc] = o;
        } else {
          float4 o; o.x = s0; o.y = s1; o.z = s2; o.w = s3;
          *(float4*)&cval[base + 4 * (tc - 8)] = o;
        }
      }
    }
  }
}

// ---------------------------------------------------------------------------
// sim: per block one (n,f), 64 l-rows vs all 256 centers, K=32 (k-major LDS).
// Thread 8 rows {4tr+i, 32+4tr+i} x 8 centers {4tc+c, 128+4tc+c}; inner loop
// read-then-use (4 ds_read_b128 + 64 fmaf per k). X rows l2-normalized during
// staging. Argmax of a*sim+b per row via 32-lane shfl_xor (min-index tie);
// gather c_value, scale by sigmoid(max), write dispatched IN PLACE over xn.
// ---------------------------------------------------------------------------
__global__ __launch_bounds__(256) void sim_k(
    float* __restrict__ xn, const float* __restrict__ cpn,
    const float* __restrict__ cval, const float* __restrict__ alphap,
    const float* __restrict__ betap) {
  __shared__ float Xs[32 * 68];    //  8.7 KB (stride 68, rows 0..63)
  __shared__ float Cs[32 * 260];   // 33.3 KB (stride 260, centers 0..255)
  int t = threadIdx.x;
  int tc = t & 31, tr = t >> 5;    // 32 thread-cols x 8 thread-rows
  int lt = blockIdx.x & 63;
  int nf = blockIdx.x >> 6;        // 0..31
  int f = nf & 7, nI = nf >> 3;
  int l0 = lt * 64;

  // stage centers: 512 4x4 (center x k) blocks, 2 per thread, reg-transpose
  const float* cp = cpn + (size_t)nf * Ss * SC;
#pragma unroll
  for (int it = 0; it < 2; it++) {
    int idx = t + 256 * it;
    int jq = idx & 7, c0 = 4 * (idx >> 3);
    int ph = ((jq >> 1) & 3) << 2;
    float4 v[4];
#pragma unroll
    for (int i = 0; i < 4; i++)
      v[i] = *(const float4*)(cp + (size_t)(c0 + i) * SC + 4 * jq);
#pragma unroll
    for (int q = 0; q < 4; q++) {
      float4 w;
      w.x = ((const float*)&v[0])[q]; w.y = ((const float*)&v[1])[q];
      w.z = ((const float*)&v[2])[q]; w.w = ((const float*)&v[3])[q];
      *(float4*)&Cs[(4 * jq + q) * 260 + (c0 ^ ph)] = w;
    }
  }
  // stage x rows 64x32 (threads 0..127), l2-normalized (8-lane shfl per row)
  if (t < 128) {
    int jq = t & 7, r0 = 4 * (t >> 3);
    int ph = ((jq >> 1) & 3) << 2;
    float4 v[4];
    float ssq[4];
#pragma unroll
    for (int i = 0; i < 4; i++) {
      v[i] = *(const float4*)(xn + ((size_t)nI * Ll + l0 + r0 + i) * Cc + f * SC + 4 * jq);
      ssq[i] = v[i].x * v[i].x + v[i].y * v[i].y + v[i].z * v[i].z + v[i].w * v[i].w;
    }
#pragma unroll
    for (int m = 1; m <= 4; m <<= 1)
#pragma unroll
      for (int i = 0; i < 4; i++) ssq[i] += __shfl_xor(ssq[i], m, 64);
#pragma unroll
    for (int i = 0; i < 4; i++) {
      float rin = 1.f / fmaxf(sqrtf(ssq[i]), 1e-12f);
      v[i].x *= rin; v[i].y *= rin; v[i].z *= rin; v[i].w *= rin;
    }
#pragma unroll
    for (int q = 0; q < 4; q++) {
      float4 w;
      w.x = ((const float*)&v[0])[q]; w.y = ((const float*)&v[1])[q];
      w.z = ((const float*)&v[2])[q]; w.w = ((const float*)&v[3])[q];
      *(float4*)&Xs[(4 * jq + q) * 68 + (r0 ^ ph)] = w;
    }
  }
  __syncthreads();

  float acc[8][8];
#pragma unroll
  for (int i = 0; i < 8; i++)
#pragma unroll
    for (int c = 0; c < 8; c++) acc[i][c] = 0.f;

  int ia0 = 4 * tr, ib0 = 4 * tc;
#pragma unroll 8
  for (int k = 0; k < 32; k++) {
    int ph = PHI(k);
    int ja = ia0 ^ ph, jb = ib0 ^ ph;
    float4 a0 = *(const float4*)&Xs[k * 68 + ja];
    float4 a1 = *(const float4*)&Xs[k * 68 + 32 + ja];
    float4 b0 = *(const float4*)&Cs[k * 260 + jb];
    float4 b1 = *(const float4*)&Cs[k * 260 + 128 + jb];
    const float* af0 = (const float*)&a0;
    const float* af1 = (const float*)&a1;
    const float* bf0 = (const float*)&b0;
    const float* bf1 = (const float*)&b1;
#pragma unroll
    for (int i = 0; i < 4; i++) {
#pragma unroll
      for (int c = 0; c < 4; c++) {
        acc[i][c]         = fmaf(af0[i], bf0[c], acc[i][c]);
        acc[i][c + 4]     = fmaf(af0[i], bf1[c], acc[i][c + 4]);
        acc[i + 4][c]     = fmaf(af1[i], bf0[c], acc[i + 4][c]);
        acc[i + 4][c + 4] = fmaf(af1[i], bf1[c], acc[i + 4][c + 4]);
      }
    }
  }

  float a = alphap[0], bt = betap[0];
#pragma unroll
  for (int i = 0; i < 8; i++) {
    int row = (i < 4) ? (4 * tr + i) : (32 + 4 * tr + (i - 4));
    float best = -3.0e38f;
    int bi = 0;
#pragma unroll
    for (int c = 0; c < 8; c++) {
      float tv = fmaf(a, acc[i][c], bt);
      int s = (c < 4) ? (4 * tc + c) : (128 + 4 * tc + (c - 4));  // increasing
      if (tv > best) { best = tv; bi = s; }
    }
#pragma unroll
    for (int m = 1; m <= 16; m <<= 1) {  // reduce across the 32 tc-lanes
      float ov = __shfl_xor(best, m, 64);
      int oi = __shfl_xor(bi, m, 64);
      if (ov > best || (ov == best && oi < bi)) { best = ov; bi = oi; }
    }
    float mv = 1.f / (1.f + expf(-best));
    const float* cvp = cval + ((size_t)nf * Ss + bi) * SC;
    float* orow = xn + ((size_t)nI * Ll + l0 + row) * Cc + f * SC;
    orow[tc] = cvp[tc] * mv;
  }
}

// ---------------------------------------------------------------------------
// out = dispatched @ Wm^T + bm
// ---------------------------------------------------------------------------
__global__ __launch_bounds__(256) void out_k(
    const float* __restrict__ xn, const float* __restrict__ Wm,
    const float* __restrict__ bm, float* __restrict__ out) {
  __shared__ float As[32 * LSTR];
  __shared__ float Bs[32 * LSTR];
  int t = threadIdx.x;
  size_t row0 = (size_t)(blockIdx.x >> 1) * 128;
  int cb0 = (blockIdx.x & 1) * 128;
  float acc[8][8];
  gemm_tile(xn, Wm, bm, row0, cb0, As, Bs, t, acc);
  store_tile(out, row0, cb0, Cc, t, acc);
}

// ---------------------------------------------------------------------------
extern "C" void kernel_launch(void* const* d_in, const int* in_sizes, int n_in,
                              void* d_out, int out_size, void* d_ws, size_t ws_size,
                              hipStream_t stream) {
  const float* x0      = (const float*)d_in[0];
  const float* center1 = (const float*)d_in[1];
  const float* W0      = (const float*)d_in[2];
  const float* b0      = (const float*)d_in[3];
  const float* W1      = (const float*)d_in[4];
  const float* b1      = (const float*)d_in[5];
  const float* Wm      = (const float*)d_in[6];
  const float* bm      = (const float*)d_in[7];
  const float* alpha   = (const float*)d_in[8];
  const float* beta    = (const float*)d_in[9];
  float* out = (float*)d_out;
  float* ws  = (float*)d_ws;

  float* xn   = ws;                              // 16 MB: x0p, then dispatched in-place
  float* cpn  = xn + (size_t)Nn * Ll * Cc;       // 1 MB
  float* cval = cpn + (size_t)Nn * FC * Ss * SC; // 1 MB  (total 18 MB)

  x0p_c1_k<<<dim3(288), dim3(256), 0, stream>>>(
      x0, W0, b0, center1, W1, b1, xn, cpn, cval);
  sim_k<<<dim3(32 * 64), dim3(256), 0, stream>>>(xn, cpn, cval, alpha, beta);
  out_k<<<dim3(256), dim3(256), 0, stream>>>(xn, Wm, bm, out);
}

// Round 8
// 192.993 us; speedup vs baseline: 2.4262x; 1.1042x over previous
//
#include <hip/hip_runtime.h>
#include <math.h>

// Problem constants (fixed by setup_inputs)
#define Nn 4
#define Ll 4096
#define Ss 256
#define Cc 256
#define FC 8
#define SC 32

#define LSTR 132                        // k-major LDS stride (words)
#define PHI(k) ((((k) >> 3) & 3) << 2)  // row-XOR swizzle (const per k-octet)

typedef __attribute__((ext_vector_type(8))) short short8;   // 8 bf16 frag
typedef __attribute__((ext_vector_type(4))) float f32x4;    // MFMA acc

__device__ __forceinline__ unsigned short f2bf(float x) {   // RTNE f32->bf16
  unsigned int u = __float_as_uint(x);
  return (unsigned short)((u + 0x7FFFu + ((u >> 16) & 1u)) >> 16);
}

// ---------------------------------------------------------------------------
// k-major fp32 GEMM tile (round-7 proven): acc[8][8] = A @ W^T + bias.
// ---------------------------------------------------------------------------
__device__ __forceinline__ void gemm_tile(
    const float* __restrict__ A, const float* __restrict__ W,
    const float* __restrict__ bias, size_t row0, int cb0,
    float* __restrict__ As, float* __restrict__ Bs, int t, float acc[8][8]) {
  int tc = t & 15, tr = (t >> 4) & 15;
  int jq = t & 7, r0s = 4 * (t >> 3);  // staging 4x4 block
  int phS = ((jq >> 1) & 3) << 2;      // PHI(4jq+q), q<4
  int woff = (4 * jq) * LSTR + (r0s ^ phS);

  float4 bb0 = *(const float4*)&bias[cb0 + 4 * tc];
  float4 bb1 = *(const float4*)&bias[cb0 + 64 + 4 * tc];
#pragma unroll
  for (int i = 0; i < 8; i++) {
    acc[i][0] = bb0.x; acc[i][1] = bb0.y; acc[i][2] = bb0.z; acc[i][3] = bb0.w;
    acc[i][4] = bb1.x; acc[i][5] = bb1.y; acc[i][6] = bb1.z; acc[i][7] = bb1.w;
  }

  float4 pa[4], pb[4];
#pragma unroll
  for (int i = 0; i < 4; i++) {
    pa[i] = *(const float4*)(A + (row0 + r0s + i) * Cc + 4 * jq);
    pb[i] = *(const float4*)(W + (size_t)(cb0 + r0s + i) * Cc + 4 * jq);
  }

  for (int kt = 0; kt < 8; kt++) {
    __syncthreads();
#pragma unroll
    for (int q = 0; q < 4; q++) {
      float4 wa, wb;
      wa.x = ((const float*)&pa[0])[q]; wa.y = ((const float*)&pa[1])[q];
      wa.z = ((const float*)&pa[2])[q]; wa.w = ((const float*)&pa[3])[q];
      wb.x = ((const float*)&pb[0])[q]; wb.y = ((const float*)&pb[1])[q];
      wb.z = ((const float*)&pb[2])[q]; wb.w = ((const float*)&pb[3])[q];
      *(float4*)&As[woff + q * LSTR] = wa;
      *(float4*)&Bs[woff + q * LSTR] = wb;
    }
    __syncthreads();
    // prefetch kt+1 AFTER the barrier: hides behind compute (barrier-drain fix)
    if (kt < 7) {
#pragma unroll
      for (int i = 0; i < 4; i++) {
        pa[i] = *(const float4*)(A + (row0 + r0s + i) * Cc + (kt + 1) * 32 + 4 * jq);
        pb[i] = *(const float4*)(W + (size_t)(cb0 + r0s + i) * Cc + (kt + 1) * 32 + 4 * jq);
      }
    }

    int ia0 = 4 * tr, ib0 = 4 * tc;
#pragma unroll 8
    for (int k = 0; k < 32; k++) {
      int ph = PHI(k);
      int ja = ia0 ^ ph, jb = ib0 ^ ph;
      float4 a0 = *(const float4*)&As[k * LSTR + ja];
      float4 a1 = *(const float4*)&As[k * LSTR + 64 + ja];
      float4 b0 = *(const float4*)&Bs[k * LSTR + jb];
      float4 b1 = *(const float4*)&Bs[k * LSTR + 64 + jb];
      const float* af0 = (const float*)&a0;
      const float* af1 = (const float*)&a1;
      const float* bf0 = (const float*)&b0;
      const float* bf1 = (const float*)&b1;
#pragma unroll
      for (int i = 0; i < 4; i++) {
#pragma unroll
        for (int c = 0; c < 4; c++) {
          acc[i][c]         = fmaf(af0[i], bf0[c], acc[i][c]);
          acc[i][c + 4]     = fmaf(af0[i], bf1[c], acc[i][c + 4]);
          acc[i + 4][c]     = fmaf(af1[i], bf0[c], acc[i + 4][c]);
          acc[i + 4][c + 4] = fmaf(af1[i], bf1[c], acc[i + 4][c + 4]);
        }
      }
    }
  }
}

__device__ __forceinline__ void store_tile(
    float* __restrict__ C, size_t row0, int cb0, int ldc, int t,
    const float acc[8][8]) {
  int tc = t & 15, tr = (t >> 4) & 15;
#pragma unroll
  for (int i = 0; i < 8; i++) {
    int r = (i < 4) ? (4 * tr + i) : (64 + 4 * tr + (i - 4));
    float4 o0, o1;
    o0.x = acc[i][0]; o0.y = acc[i][1]; o0.z = acc[i][2]; o0.w = acc[i][3];
    o1.x = acc[i][4]; o1.y = acc[i][5]; o1.z = acc[i][6]; o1.w = acc[i][7];
    float* cr = C + (row0 + r) * (size_t)ldc + cb0;
    *(float4*)(cr + 4 * tc) = o0;
    *(float4*)(cr + 64 + 4 * tc) = o1;
  }
}

// ---------------------------------------------------------------------------
// Fused kernel 1 (unchanged from round 7).
// ---------------------------------------------------------------------------
__global__ __launch_bounds__(256) void x0p_c1_k(
    const float* __restrict__ x0, const float* __restrict__ W0,
    const float* __restrict__ b0, const float* __restrict__ center1,
    const float* __restrict__ W1, const float* __restrict__ b1,
    float* __restrict__ xn, float* __restrict__ cpn, float* __restrict__ cval) {
  __shared__ float As[32 * LSTR];
  __shared__ float Bs[32 * LSTR];
  int t = threadIdx.x;
  int tc = t & 15, tr = (t >> 4) & 15;
  int b = blockIdx.x;
  float acc[8][8];

  if (b < 256) {
    size_t row0 = (size_t)(b >> 1) * 128;
    int cb0 = (b & 1) * 128;
    gemm_tile(x0, W0, b0, row0, cb0, As, Bs, t, acc);
    store_tile(xn, row0, cb0, Cc, t, acc);
  } else {
    int b2 = b - 256;
    size_t row0 = (size_t)(b2 >> 2) * 128;  // M=1024 (n*256+s)
    int cb0 = (b2 & 3) * 128;               // N=512
    gemm_tile(center1, W1, b1, row0, cb0, As, Bs, t, acc);
    int fb = cb0 >> 6;
#pragma unroll
    for (int i = 0; i < 8; i++) {
      int r = (i < 4) ? (4 * tr + i) : (64 + 4 * tr + (i - 4));
      int crow = (int)row0 + r;
      int nI = crow >> 8, s = crow & 255;
#pragma unroll
      for (int h = 0; h < 2; h++) {
        float s0 = acc[i][4 * h + 0], s1 = acc[i][4 * h + 1];
        float s2 = acc[i][4 * h + 2], s3 = acc[i][4 * h + 3];
        float ss = s0 * s0 + s1 * s1 + s2 * s2 + s3 * s3;
        ss += __shfl_xor(ss, 1, 64);
        ss += __shfl_xor(ss, 2, 64);
        ss += __shfl_xor(ss, 4, 64);
        float rin = 1.f / fmaxf(sqrtf(ss), 1e-12f);
        int f = fb + h;
        size_t base = (((size_t)nI * FC + f) * Ss + s) * SC;
        if (tc < 8) {
          float4 o; o.x = s0 * rin; o.y = s1 * rin; o.z = s2 * rin; o.w = s3 * rin;
          *(float4*)&cpn[base + 4 * tc] = o;
        } else {
          float4 o; o.x = s0; o.y = s1; o.z = s2; o.w = s3;
          *(float4*)&cval[base + 4 * (tc - 8)] = o;
        }
      }
    }
  }
}

// ---------------------------------------------------------------------------
// sim (unchanged from round 7).
// ---------------------------------------------------------------------------
__global__ __launch_bounds__(256) void sim_k(
    float* __restrict__ xn, const float* __restrict__ cpn,
    const float* __restrict__ cval, const float* __restrict__ alphap,
    const float* __restrict__ betap) {
  __shared__ float Xs[32 * 68];
  __shared__ float Cs[32 * 260];
  int t = threadIdx.x;
  int tc = t & 31, tr = t >> 5;
  int lt = blockIdx.x & 63;
  int nf = blockIdx.x >> 6;
  int f = nf & 7, nI = nf >> 3;
  int l0 = lt * 64;

  const float* cp = cpn + (size_t)nf * Ss * SC;
#pragma unroll
  for (int it = 0; it < 2; it++) {
    int idx = t + 256 * it;
    int jq = idx & 7, c0 = 4 * (idx >> 3);
    int ph = ((jq >> 1) & 3) << 2;
    float4 v[4];
#pragma unroll
    for (int i = 0; i < 4; i++)
      v[i] = *(const float4*)(cp + (size_t)(c0 + i) * SC + 4 * jq);
#pragma unroll
    for (int q = 0; q < 4; q++) {
      float4 w;
      w.x = ((const float*)&v[0])[q]; w.y = ((const float*)&v[1])[q];
      w.z = ((const float*)&v[2])[q]; w.w = ((const float*)&v[3])[q];
      *(float4*)&Cs[(4 * jq + q) * 260 + (c0 ^ ph)] = w;
    }
  }
  if (t < 128) {
    int jq = t & 7, r0 = 4 * (t >> 3);
    int ph = ((jq >> 1) & 3) << 2;
    float4 v[4];
    float ssq[4];
#pragma unroll
    for (int i = 0; i < 4; i++) {
      v[i] = *(const float4*)(xn + ((size_t)nI * Ll + l0 + r0 + i) * Cc + f * SC + 4 * jq);
      ssq[i] = v[i].x * v[i].x + v[i].y * v[i].y + v[i].z * v[i].z + v[i].w * v[i].w;
    }
#pragma unroll
    for (int m = 1; m <= 4; m <<= 1)
#pragma unroll
      for (int i = 0; i < 4; i++) ssq[i] += __shfl_xor(ssq[i], m, 64);
#pragma unroll
    for (int i = 0; i < 4; i++) {
      float rin = 1.f / fmaxf(sqrtf(ssq[i]), 1e-12f);
      v[i].x *= rin; v[i].y *= rin; v[i].z *= rin; v[i].w *= rin;
    }
#pragma unroll
    for (int q = 0; q < 4; q++) {
      float4 w;
      w.x = ((const float*)&v[0])[q]; w.y = ((const float*)&v[1])[q];
      w.z = ((const float*)&v[2])[q]; w.w = ((const float*)&v[3])[q];
      *(float4*)&Xs[(4 * jq + q) * 68 + (r0 ^ ph)] = w;
    }
  }
  __syncthreads();

  float acc[8][8];
#pragma unroll
  for (int i = 0; i < 8; i++)
#pragma unroll
    for (int c = 0; c < 8; c++) acc[i][c] = 0.f;

  int ia0 = 4 * tr, ib0 = 4 * tc;
#pragma unroll 8
  for (int k = 0; k < 32; k++) {
    int ph = PHI(k);
    int ja = ia0 ^ ph, jb = ib0 ^ ph;
    float4 a0 = *(const float4*)&Xs[k * 68 + ja];
    float4 a1 = *(const float4*)&Xs[k * 68 + 32 + ja];
    float4 b0 = *(const float4*)&Cs[k * 260 + jb];
    float4 b1 = *(const float4*)&Cs[k * 260 + 128 + jb];
    const float* af0 = (const float*)&a0;
    const float* af1 = (const float*)&a1;
    const float* bf0 = (const float*)&b0;
    const float* bf1 = (const float*)&b1;
#pragma unroll
    for (int i = 0; i < 4; i++) {
#pragma unroll
      for (int c = 0; c < 4; c++) {
        acc[i][c]         = fmaf(af0[i], bf0[c], acc[i][c]);
        acc[i][c + 4]     = fmaf(af0[i], bf1[c], acc[i][c + 4]);
        acc[i + 4][c]     = fmaf(af1[i], bf0[c], acc[i + 4][c]);
        acc[i + 4][c + 4] = fmaf(af1[i], bf1[c], acc[i + 4][c + 4]);
      }
    }
  }

  float a = alphap[0], bt = betap[0];
#pragma unroll
  for (int i = 0; i < 8; i++) {
    int row = (i < 4) ? (4 * tr + i) : (32 + 4 * tr + (i - 4));
    float best = -3.0e38f;
    int bi = 0;
#pragma unroll
    for (int c = 0; c < 8; c++) {
      float tv = fmaf(a, acc[i][c], bt);
      int s = (c < 4) ? (4 * tc + c) : (128 + 4 * tc + (c - 4));
      if (tv > best) { best = tv; bi = s; }
    }
#pragma unroll
    for (int m = 1; m <= 16; m <<= 1) {
      float ov = __shfl_xor(best, m, 64);
      int oi = __shfl_xor(bi, m, 64);
      if (ov > best || (ov == best && oi < bi)) { best = ov; bi = oi; }
    }
    float mv = 1.f / (1.f + expf(-best));
    const float* cvp = cval + ((size_t)nf * Ss + bi) * SC;
    float* orow = xn + ((size_t)nI * Ll + l0 + row) * Cc + f * SC;
    orow[tc] = cvp[tc] * mv;
  }
}

// ---------------------------------------------------------------------------
// out = dispatched @ Wm^T + bm via bf16 MFMA, NO LDS.
// Grid 256 blocks (128 M-tiles x 2 N-tiles), 256 thr = 4 waves; wave computes
// a 64x64 tile = 4x4 grid of 16x16x32 MFMAs. Fragments loaded DIRECTLY from
// global as fp32 (line-coalesced: one frag instr = 16 rows x 16 B, and the 4
// quads of a frag cover a full 64 B k-slab per row), converted to bf16 in
// registers (RTNE). A = xn (L3), B = Wm (L2-resident). bf16 rounding adds
// ~2e-3 abs error -- far under the 4.2e-2 threshold; argmax path untouched.
// A-frag layout: lane holds A[m = lane&15][k = (lane>>4)*8 + j], j=0..7.
// B-frag: lane holds W[n = lane&15][k = quad*8 + j] (B^T pattern).
// C/D: col = lane&15, row = (lane>>4)*4 + reg  [m89-verified].
// ---------------------------------------------------------------------------
__global__ __launch_bounds__(256) void out_mfma_k(
    const float* __restrict__ xn, const float* __restrict__ Wm,
    const float* __restrict__ bm, float* __restrict__ out) {
  int t = threadIdx.x;
  int wave = t >> 6, lane = t & 63;
  int quad = lane >> 4, l15 = lane & 15;
  size_t m0 = (size_t)(blockIdx.x >> 1) * 128 + (wave & 1) * 64;
  int n0 = (blockIdx.x & 1) * 128 + (wave >> 1) * 64;

  f32x4 acc[4][4];
#pragma unroll
  for (int ni = 0; ni < 4; ni++) {
    float bv = bm[n0 + ni * 16 + l15];
    f32x4 ci = {bv, bv, bv, bv};
#pragma unroll
    for (int mi = 0; mi < 4; mi++) acc[mi][ni] = ci;
  }

  for (int kt = 0; kt < 8; kt++) {
    int k0 = kt * 32 + quad * 8;
    short8 Af[4], Bf[4];
#pragma unroll
    for (int mi = 0; mi < 4; mi++) {
      const float* p = xn + (m0 + mi * 16 + l15) * Cc + k0;
      float4 lo = *(const float4*)p;
      float4 hi = *(const float4*)(p + 4);
      short8 fr;
      fr[0] = (short)f2bf(lo.x); fr[1] = (short)f2bf(lo.y);
      fr[2] = (short)f2bf(lo.z); fr[3] = (short)f2bf(lo.w);
      fr[4] = (short)f2bf(hi.x); fr[5] = (short)f2bf(hi.y);
      fr[6] = (short)f2bf(hi.z); fr[7] = (short)f2bf(hi.w);
      Af[mi] = fr;
    }
#pragma unroll
    for (int ni = 0; ni < 4; ni++) {
      const float* p = Wm + (size_t)(n0 + ni * 16 + l15) * Cc + k0;
      float4 lo = *(const float4*)p;
      float4 hi = *(const float4*)(p + 4);
      short8 fr;
      fr[0] = (short)f2bf(lo.x); fr[1] = (short)f2bf(lo.y);
      fr[2] = (short)f2bf(lo.z); fr[3] = (short)f2bf(lo.w);
      fr[4] = (short)f2bf(hi.x); fr[5] = (short)f2bf(hi.y);
      fr[6] = (short)f2bf(hi.z); fr[7] = (short)f2bf(hi.w);
      Bf[ni] = fr;
    }
#pragma unroll
    for (int mi = 0; mi < 4; mi++)
#pragma unroll
      for (int ni = 0; ni < 4; ni++)
        acc[mi][ni] = __builtin_amdgcn_mfma_f32_16x16x32_bf16(
            Af[mi], Bf[ni], acc[mi][ni], 0, 0, 0);
  }

#pragma unroll
  for (int mi = 0; mi < 4; mi++) {
#pragma unroll
    for (int reg = 0; reg < 4; reg++) {
      size_t row = m0 + mi * 16 + quad * 4 + reg;
      float* orow = out + row * Cc + n0;
#pragma unroll
      for (int ni = 0; ni < 4; ni++)
        orow[ni * 16 + l15] = acc[mi][ni][reg];
    }
  }
}

// ---------------------------------------------------------------------------
extern "C" void kernel_launch(void* const* d_in, const int* in_sizes, int n_in,
                              void* d_out, int out_size, void* d_ws, size_t ws_size,
                              hipStream_t stream) {
  const float* x0      = (const float*)d_in[0];
  const float* center1 = (const float*)d_in[1];
  const float* W0      = (const float*)d_in[2];
  const float* b0      = (const float*)d_in[3];
  const float* W1      = (const float*)d_in[4];
  const float* b1      = (const float*)d_in[5];
  const float* Wm      = (const float*)d_in[6];
  const float* bm      = (const float*)d_in[7];
  const float* alpha   = (const float*)d_in[8];
  const float* beta    = (const float*)d_in[9];
  float* out = (float*)d_out;
  float* ws  = (float*)d_ws;

  float* xn   = ws;                              // 16 MB: x0p, then dispatched in-place
  float* cpn  = xn + (size_t)Nn * Ll * Cc;       // 1 MB
  float* cval = cpn + (size_t)Nn * FC * Ss * SC; // 1 MB  (total 18 MB)

  x0p_c1_k<<<dim3(288), dim3(256), 0, stream>>>(
      x0, W0, b0, center1, W1, b1, xn, cpn, cval);
  sim_k<<<dim3(32 * 64), dim3(256), 0, stream>>>(xn, cpn, cval, alpha, beta);
  out_mfma_k<<<dim3(256), dim3(256), 0, stream>>>(xn, Wm, bm, out);
}